// Round 7
// baseline (2343.972 us; speedup 1.0000x reference)
//
#include <hip/hip_runtime.h>
#include <math.h>

#define NEGV (-1e9f)

// ws layout (float offsets):
//   OUT [B*N][512] : cols 0..127 K1, 128..255 V, 256..383 U=K2@Wout,
//                    384..511 Qfull = QR + emb@Wq[:,2:]^T  (QR folded in GEMM)
//   M   [128][512], QR [B][128] (dead after gemm -> reused as work counter),
//   QI  [B][128], SOL [B][200]
#define OUT_F   0l
#define M_F     52428800l
#define QR_F    (M_F + 65536l)
#define QI_F    (QR_F + 65536l)
#define SOL_F   (QI_F + 65536l)
#define WS_FLOATS (SOL_F + 102400l)   // 52,727,808 floats = ~211 MB (known OK)

typedef float f32x4 __attribute__((ext_vector_type(4)));

// ---------------- DPP cross-lane helpers ----------------
#define DPPF(x, ctrl, oldv) __int_as_float(__builtin_amdgcn_update_dpp( \
      __float_as_int(oldv), __float_as_int(x), ctrl, 0xF, 0xF, false))

__device__ __forceinline__ float wave_max(float x) {
  x = fmaxf(x, DPPF(x, 0x111, -INFINITY));   // row_shr:1
  x = fmaxf(x, DPPF(x, 0x112, -INFINITY));   // row_shr:2
  x = fmaxf(x, DPPF(x, 0x114, -INFINITY));   // row_shr:4
  x = fmaxf(x, DPPF(x, 0x118, -INFINITY));   // row_shr:8
  x = fmaxf(x, DPPF(x, 0x142, -INFINITY));   // row_bcast:15
  x = fmaxf(x, DPPF(x, 0x143, -INFINITY));   // row_bcast:31
  return __int_as_float(__builtin_amdgcn_readlane(__float_as_int(x), 63));
}
__device__ __forceinline__ float wave_sum(float x) {
  x = x + DPPF(x, 0x111, 0.f);
  x = x + DPPF(x, 0x112, 0.f);
  x = x + DPPF(x, 0x114, 0.f);
  x = x + DPPF(x, 0x118, 0.f);
  x = x + DPPF(x, 0x142, 0.f);
  x = x + DPPF(x, 0x143, 0.f);
  return __int_as_float(__builtin_amdgcn_readlane(__float_as_int(x), 63));
}

// ---------------- static precompute ----------------
__global__ __launch_bounds__(256)
void build_M(const float* __restrict__ Wk1, const float* __restrict__ Wv,
             const float* __restrict__ Wk2, const float* __restrict__ Wout,
             const float* __restrict__ Wq, float* __restrict__ Mbuf) {
  int g = blockIdx.x * 256 + threadIdx.x;
  int j = g >> 9, c = g & 511;
  float val;
  if (c < 128) {
    val = Wk1[c * 128 + j];
  } else if (c < 256) {
    val = Wv[(c - 128) * 128 + j];
  } else if (c < 384) {
    int d = c - 256;
    float s = 0.f;
    for (int e = 0; e < 128; ++e) s += Wk2[e * 128 + j] * Wout[e * 128 + d];
    val = s;
  } else {
    val = Wq[(c - 384) * 130 + 2 + j];
  }
  Mbuf[j * 512 + c] = val;
}

__global__ __launch_bounds__(256)
void build_Q(const float* __restrict__ rf, const float* __restrict__ Wq,
             const float* __restrict__ initn, float* __restrict__ QR,
             float* __restrict__ QI) {
  int g = blockIdx.x * 256 + threadIdx.x;   // 65536 = 512*128
  int b = g >> 7, d = g & 127;
  float qr = Wq[d * 130 + 0] * rf[b * 2 + 0] + Wq[d * 130 + 1] * rf[b * 2 + 1];
  float qi = qr;
  for (int j = 0; j < 128; ++j) qi += Wq[d * 130 + 2 + j] * initn[j];
  QR[g] = qr;
  QI[g] = qi;
}

__global__ __launch_bounds__(256)
void gemm_static(const float* __restrict__ emb, const float* __restrict__ Mbuf,
                 const float* __restrict__ bk1, const float* __restrict__ QR,
                 float* __restrict__ OUT) {
  int bid = blockIdx.x;                 // 1600 row-tiles * 8 col-tiles
  int rt = bid >> 3, ct = bid & 7;
  int r0 = rt * 64, c0 = ct * 64;
  int t = threadIdx.x, ty = t >> 4, tx = t & 15;
  int row0 = r0 + ty * 4;
  int col  = c0 + tx * 4;
  float acc[4][4] = {};
  const float* mp = Mbuf + col;
  for (int kb = 0; kb < 32; ++kb) {
    int k = kb * 4;
    float4 b0 = *(const float4*)(mp + (long)(k + 0) * 512);
    float4 b1 = *(const float4*)(mp + (long)(k + 1) * 512);
    float4 b2 = *(const float4*)(mp + (long)(k + 2) * 512);
    float4 b3 = *(const float4*)(mp + (long)(k + 3) * 512);
    float bm[4][4] = {{b0.x,b0.y,b0.z,b0.w},{b1.x,b1.y,b1.z,b1.w},
                      {b2.x,b2.y,b2.z,b2.w},{b3.x,b3.y,b3.z,b3.w}};
    #pragma unroll
    for (int rr = 0; rr < 4; ++rr) {
      float4 a4 = *(const float4*)(emb + (long)(row0 + rr) * 128 + k);
      float av[4] = {a4.x, a4.y, a4.z, a4.w};
      #pragma unroll
      for (int i = 0; i < 4; ++i)
        #pragma unroll
        for (int cc = 0; cc < 4; ++cc)
          acc[rr][cc] += av[i] * bm[i][cc];
    }
  }
  float badd[4] = {0.f, 0.f, 0.f, 0.f};
  if (c0 < 128) {
    #pragma unroll
    for (int cc = 0; cc < 4; ++cc) badd[cc] = bk1[col + cc];
  }
  #pragma unroll
  for (int rr = 0; rr < 4; ++rr) {
    int row = row0 + rr;
    float v[4];
    #pragma unroll
    for (int cc = 0; cc < 4; ++cc) v[cc] = acc[rr][cc] + badd[cc];
    if (col >= 384) {                   // fold QR -> full q rows
      int bb = row / 200;
      #pragma unroll
      for (int cc = 0; cc < 4; ++cc) v[cc] += QR[bb * 128 + (col - 384) + cc];
    }
    float4 v4; v4.x = v[0]; v4.y = v[1]; v4.z = v[2]; v4.w = v[3];
    *(float4*)(OUT + (long)row * 512 + col) = v4;
  }
}

__global__ void init_ctr(int* __restrict__ c) { *c = 0; }

// ---------------- decode: persistent work-stealing ----------------
// V (25 floats/thread) in registers; U STREAMED from L2 each step (phase C)
// with an opaque-zero address perturbation so LICM cannot hoist it back into
// registers (the hoisted form spilled at the 64-VGPR allocation, rounds 4-6).
__global__
__attribute__((amdgpu_flat_work_group_size(1024, 1024), amdgpu_waves_per_eu(4, 4)))
void decode(const float* __restrict__ OUT, const float* __restrict__ QI,
            int* __restrict__ ctr, float* __restrict__ sol,
            float* __restrict__ out) {
  __shared__ float k1t[25600];                 // [d][n]
  __shared__ float at[1600];                   // attn [h][n]
  __shared__ __align__(16) float mhal[128];
  __shared__ float lg[200];
  __shared__ float qv[128];
  __shared__ int   bci;
  __shared__ int   bsel;

  const int t = threadIdx.x;
  const int lane = t & 63, wave = t >> 6;
  const int o = t >> 3, q8 = t & 7;
  const int m4 = t >> 2, j4 = t & 3;

  for (;;) {
    if (t == 0) bsel = atomicAdd(ctr, 1);
    __syncthreads();
    const int b = bsel;
    if (b >= 512) break;
    const float* outb = OUT + (long)b * 200 * 512;

    // K1 -> LDS (transpose to [d][n], conflict-free reads later)
    for (int k = 0; k < 25; ++k) {
      int f = k * 1024 + t;
      int n = f >> 7, d = f & 127;
      k1t[d * 200 + n] = outb[n * 512 + d];
    }
    // V: thread (o, q8) holds V[q8*25+i][o], i<25, as SSA vectors
    f32x4 vr0 = {}, vr1 = {}, vr2 = {}, vr3 = {}, vr4 = {}, vr5 = {};
    float v24;
    {
      const float* vp = outb + 128 + o;
      #pragma unroll
      for (int e = 0; e < 4; ++e) vr0[e] = vp[(q8 * 25 + e) * 512];
      #pragma unroll
      for (int e = 0; e < 4; ++e) vr1[e] = vp[(q8 * 25 + 4 + e) * 512];
      #pragma unroll
      for (int e = 0; e < 4; ++e) vr2[e] = vp[(q8 * 25 + 8 + e) * 512];
      #pragma unroll
      for (int e = 0; e < 4; ++e) vr3[e] = vp[(q8 * 25 + 12 + e) * 512];
      #pragma unroll
      for (int e = 0; e < 4; ++e) vr4[e] = vp[(q8 * 25 + 16 + e) * 512];
      #pragma unroll
      for (int e = 0; e < 4; ++e) vr5[e] = vp[(q8 * 25 + 20 + e) * 512];
      v24 = vp[(q8 * 25 + 24) * 512];
    }
    if (t < 128) qv[t] = QI[b * 128 + t];   // step-0 query

    int mk = 0;        // per-lane mask bits (node = lane + 64k), waves 0-7
    bool cm = false;   // node m4 masked, threads < 800
    bool live = true, picked0 = false;
    float llsum = 0.f, chose = 0.f;

    __syncthreads();

    for (int st = 0; st < 200; ++st) {
      // ---- A: scores + softmax (wave h = head h) ----
      if (wave < 8) {
        float q16[16];
        #pragma unroll
        for (int d = 0; d < 16; ++d) q16[d] = qv[wave * 16 + d];
        float sv[4];
        float mx = -INFINITY;
        #pragma unroll
        for (int k = 0; k < 4; ++k) {
          int n = lane + 64 * k;
          float s = -INFINITY;
          if (n < 200) {
            float a = 0.f;
            #pragma unroll
            for (int d = 0; d < 16; ++d)
              a += q16[d] * k1t[(wave * 16 + d) * 200 + n];
            s = a * 0.25f;
            if (mk & (1 << k)) s = NEGV;
          }
          sv[k] = s;
          mx = fmaxf(mx, s);
        }
        float vmax = wave_max(mx);
        float ls = 0.f;
        #pragma unroll
        for (int k = 0; k < 4; ++k) { sv[k] = expf(sv[k] - vmax); ls += sv[k]; }
        ls = wave_sum(ls);
        #pragma unroll
        for (int k = 0; k < 4; ++k) {
          int n = lane + 64 * k;
          if (n < 200) at[wave * 200 + n] = sv[k] / ls;
        }
      }
      __syncthreads();

      // ---- B: mha[o] = sum_n attn[h][n] * V[n][o] ----
      {
        const int h2 = t >> 7;
        const float* ap = at + h2 * 200 + q8 * 25;
        float a = 0.f;
        #pragma unroll
        for (int e = 0; e < 4; ++e) a += ap[e] * vr0[e];
        #pragma unroll
        for (int e = 0; e < 4; ++e) a += ap[4 + e] * vr1[e];
        #pragma unroll
        for (int e = 0; e < 4; ++e) a += ap[8 + e] * vr2[e];
        #pragma unroll
        for (int e = 0; e < 4; ++e) a += ap[12 + e] * vr3[e];
        #pragma unroll
        for (int e = 0; e < 4; ++e) a += ap[16 + e] * vr4[e];
        #pragma unroll
        for (int e = 0; e < 4; ++e) a += ap[20 + e] * vr5[e];
        a += ap[24] * v24;
        a += DPPF(a, 0xB1, 0.f);    // ^1 quad_perm
        a += DPPF(a, 0x4E, 0.f);    // ^2 quad_perm
        a += DPPF(a, 0x141, 0.f);   // row_half_mirror: partner quad's sum
        if (q8 == 0) mhal[o] = a;
      }
      __syncthreads();

      // ---- C: logits[m] = 10*tanh((mha . U[m]) / sqrt(128)), U streamed ----
      if (t < 800) {
        int zz;
        asm volatile("v_mov_b32 %0, 0" : "=v"(zz));  // opaque 0: blocks LICM
        const float* up = outb + m4 * 512 + 256 + j4 * 32 + zz;
        f32x4 u0 = *(const f32x4*)(up + 0);
        f32x4 u1 = *(const f32x4*)(up + 4);
        f32x4 u2 = *(const f32x4*)(up + 8);
        f32x4 u3 = *(const f32x4*)(up + 12);
        f32x4 u4 = *(const f32x4*)(up + 16);
        f32x4 u5 = *(const f32x4*)(up + 20);
        f32x4 u6 = *(const f32x4*)(up + 24);
        f32x4 u7 = *(const f32x4*)(up + 28);
        const f32x4 m0 = *(const f32x4*)(&mhal[j4 * 32 + 0]);
        const f32x4 m1 = *(const f32x4*)(&mhal[j4 * 32 + 4]);
        const f32x4 m2 = *(const f32x4*)(&mhal[j4 * 32 + 8]);
        const f32x4 m3 = *(const f32x4*)(&mhal[j4 * 32 + 12]);
        const f32x4 m4v = *(const f32x4*)(&mhal[j4 * 32 + 16]);
        const f32x4 m5 = *(const f32x4*)(&mhal[j4 * 32 + 20]);
        const f32x4 m6 = *(const f32x4*)(&mhal[j4 * 32 + 24]);
        const f32x4 m7 = *(const f32x4*)(&mhal[j4 * 32 + 28]);
        float a = 0.f;
        #pragma unroll
        for (int e = 0; e < 4; ++e) a += m0[e] * u0[e];
        #pragma unroll
        for (int e = 0; e < 4; ++e) a += m1[e] * u1[e];
        #pragma unroll
        for (int e = 0; e < 4; ++e) a += m2[e] * u2[e];
        #pragma unroll
        for (int e = 0; e < 4; ++e) a += m3[e] * u3[e];
        #pragma unroll
        for (int e = 0; e < 4; ++e) a += m4v[e] * u4[e];
        #pragma unroll
        for (int e = 0; e < 4; ++e) a += m5[e] * u5[e];
        #pragma unroll
        for (int e = 0; e < 4; ++e) a += m6[e] * u6[e];
        #pragma unroll
        for (int e = 0; e < 4; ++e) a += m7[e] * u7[e];
        a += DPPF(a, 0xB1, 0.f);
        a += DPPF(a, 0x4E, 0.f);
        if (j4 == 0) {
          float l = 10.f * tanhf(a / 11.313708498984761f);
          lg[m4] = cm ? NEGV : l;
        }
      }
      __syncthreads();

      // ---- D: argmax -> issue q-row load -> lse (overlaps load) ----
      if (wave < 8) {
        float lv[4];
        float mx = -INFINITY;
        #pragma unroll
        for (int k = 0; k < 4; ++k) {
          int n = lane + 64 * k;
          lv[k] = (n < 200) ? lg[n] : -INFINITY;
          mx = fmaxf(mx, lv[k]);
        }
        float vmax = wave_max(mx);
        int bidx = -1;
        #pragma unroll
        for (int k = 0; k < 4; ++k) {
          unsigned long long bm =
              __ballot((lane + 64 * k < 200) && (lv[k] == vmax));
          if (bidx < 0 && bm != 0ull) bidx = k * 64 + (int)__builtin_ctzll(bm);
        }
        int nxt = live ? bidx : 0;
        if (t < 128) qv[t] = outb[(long)nxt * 512 + 384 + t];
        float e = 0.f;
        #pragma unroll
        for (int k = 0; k < 4; ++k) e += expf(lv[k] - vmax);
        float se_ = wave_sum(e);
        float lse = logf(se_);
        if (t == 0) {
          chose = live ? (-lse) : ((lv[0] - vmax) - lse);
          out[2048 + (long)b * 200 + st] = (float)nxt;
          bci = nxt;
        }
      }
      __syncthreads();

      int nxt = bci;
      if (!live) {
        if (t == 0) llsum += chose * (float)(200 - st);
        for (int s2 = st + 1 + t; s2 < 200; s2 += 1024)
          out[2048 + (long)b * 200 + s2] = 0.f;
        break;
      }
      if (t == 0) llsum += chose;
      if (wave < 8 && (nxt & 63) == lane) mk |= 1 << (nxt >> 6);
      if (t < 800 && nxt == m4) cm = true;
      if (nxt == 0) { live = false; picked0 = true; }
    }

    if (t == 0) out[1536 + b] = picked0 ? llsum : 0.f;
    if (t < 800 && j4 == 0) {
      float s = (m4 == 0) ? 1.f : ((picked0 && cm) ? 1.f : 0.f);
      sol[(long)b * 200 + m4] = s;
    }
    __syncthreads();   // protect LDS reuse before next grab
  }
}

// ---------------- cost ----------------
__global__ __launch_bounds__(256)
void cost_kernel(const float* __restrict__ x, const float* __restrict__ rf,
                 const float* __restrict__ sol, float* __restrict__ out) {
  __shared__ float solL[256];
  __shared__ float red[8];
  const int b = blockIdx.x, t = threadIdx.x;
  solL[t] = (t < 200) ? sol[b * 200 + t] : 0.f;
  __syncthreads();
  const float* x0 = x + (long)b * 40000;
  const float* x1 = x + 20480000l + (long)b * 40000;
  float a1 = 0.f, a2 = 0.f;
  if (t < 200) {
    for (int i = 0; i < 200; ++i) {
      if (solL[i] != 0.f) {
        a1 += x0[i * 200 + t];
        a2 += x1[i * 200 + t];
      }
    }
    float w = solL[t];
    a1 *= w; a2 *= w;
  }
  #pragma unroll
  for (int off = 32; off > 0; off >>= 1) {
    a1 += __shfl_xor(a1, off);
    a2 += __shfl_xor(a2, off);
  }
  if ((t & 63) == 0) { red[(t >> 6) * 2] = a1; red[(t >> 6) * 2 + 1] = a2; }
  __syncthreads();
  if (t == 0) {
    float f1 = red[0] + red[2] + red[4] + red[6];
    float f2 = red[1] + red[3] + red[5] + red[7];
    out[b]        = -(f1 * rf[0] + f2 * rf[1]);
    out[512 + b]  = f1;
    out[1024 + b] = f2;
  }
}

extern "C" void kernel_launch(void* const* d_in, const int* in_sizes, int n_in,
                              void* d_out, int out_size, void* d_ws, size_t ws_size,
                              hipStream_t stream) {
  const float* x     = (const float*)d_in[0];
  const float* rf    = (const float*)d_in[1];
  const float* emb   = (const float*)d_in[2];
  const float* Wk1   = (const float*)d_in[4];
  const float* bk1   = (const float*)d_in[5];
  const float* Wv    = (const float*)d_in[6];
  const float* Wk2   = (const float*)d_in[7];
  const float* Wout  = (const float*)d_in[8];
  const float* Wq    = (const float*)d_in[9];
  const float* initn = (const float*)d_in[10];
  float* out = (float*)d_out;
  float* ws  = (float*)d_ws;

  if (ws_size < (size_t)WS_FLOATS * 4) return;

  float* OUTb = ws + OUT_F;
  float* Mb   = ws + M_F;
  float* QRb  = ws + QR_F;   // dead after gemm; first 4 bytes reused as counter
  float* QIb  = ws + QI_F;
  float* solb = ws + SOL_F;

  build_M<<<256, 256, 0, stream>>>(Wk1, Wv, Wk2, Wout, Wq, Mb);
  build_Q<<<256, 256, 0, stream>>>(rf, Wq, initn, QRb, QIb);
  gemm_static<<<12800, 256, 0, stream>>>(emb, Mb, bk1, QRb, OUTb);
  init_ctr<<<1, 1, 0, stream>>>((int*)QRb);
  decode<<<256, 1024, 0, stream>>>(OUTb, QIb, (int*)QRb, solb, out);
  cost_kernel<<<512, 256, 0, stream>>>(x, rf, solb, out);
}